// Round 1
// baseline (1990.609 us; speedup 1.0000x reference)
//
#include <hip/hip_runtime.h>

// Grid4D quadrilinear sample, align_corners=True.
// grid: [R=8, X=9, Y=9, U=512, V=512] fp32 (648 MB)
// xyuv: [N, 4] fp32 in [0,1]; min=0, max=1 (read generally anyway)
// out:  [N, 8] fp32
//
// Baseline: one thread per (point, r). 8 threads share a point's coords
// (broadcast float4 load). Each thread gathers 16 grid scalars for its r,
// does the full quadrilinear weight math in registers, writes one coalesced
// float (out[n*8+r] -> 256B contiguous per wave).

#define RR 8
#define SX 9
#define SY 9
#define SU 512
#define SV 512

__device__ __forceinline__ void split_coord(float p, int size, int& i0, float& f) {
    // clamp into [0, size-1]; reference inputs are in-range so this only
    // guards exact-boundary / numerical edge cases.
    p = fminf(fmaxf(p, 0.0f), (float)(size - 1));
    float fl = floorf(p);
    int i = (int)fl;
    if (i > size - 2) i = size - 2;   // keep i0+1 in bounds; f becomes 1.0 at the top edge
    i0 = i;
    f = p - (float)i;
}

__global__ __launch_bounds__(256) void grid4d_kernel(
    const float4* __restrict__ xyuv,   // [N]
    const float*  __restrict__ grid,   // [8,9,9,512,512]
    const float*  __restrict__ mn,     // [4]
    const float*  __restrict__ mx,     // [4]
    float*        __restrict__ out,    // [N,8]
    int npts)
{
    int tid = blockIdx.x * blockDim.x + threadIdx.x;
    int n = tid >> 3;
    int r = tid & 7;
    if (n >= npts) return;

    float4 c = xyuv[n];

    // pos_d = (c_d - min_d) / (max_d - min_d) * (size_d - 1)
    float px = (c.x - mn[0]) / (mx[0] - mn[0]) * (float)(SX - 1);
    float py = (c.y - mn[1]) / (mx[1] - mn[1]) * (float)(SY - 1);
    float pu = (c.z - mn[2]) / (mx[2] - mn[2]) * (float)(SU - 1);
    float pv = (c.w - mn[3]) / (mx[3] - mn[3]) * (float)(SV - 1);

    int x0, y0, u0, v0;
    float fx, fy, fu, fv;
    split_coord(px, SX, x0, fx);
    split_coord(py, SY, y0, fy);
    split_coord(pu, SU, u0, fu);
    split_coord(pv, SV, v0, fv);

    float wx0 = 1.0f - fx, wx1 = fx;
    float wy0 = 1.0f - fy, wy1 = fy;
    float wu0 = 1.0f - fu, wu1 = fu;
    float wv0 = 1.0f - fv, wv1 = fv;

    const float* gr = grid + (size_t)r * (SX * SY * SU * SV);
    size_t buv = (size_t)u0 * SV + (size_t)v0;

    float acc = 0.0f;
#pragma unroll
    for (int dx = 0; dx < 2; ++dx) {
#pragma unroll
        for (int dy = 0; dy < 2; ++dy) {
            const float* g = gr + ((size_t)(x0 + dx) * SY + (size_t)(y0 + dy)) * (SU * SV) + buv;
            float a00 = g[0];
            float a01 = g[1];
            float a10 = g[SV];
            float a11 = g[SV + 1];
            float bu0 = a00 * wv0 + a01 * wv1;   // row u0
            float bu1 = a10 * wv0 + a11 * wv1;   // row u0+1
            float bil = bu0 * wu0 + bu1 * wu1;   // bilinear in (u,v)
            float wxy = (dx ? wx1 : wx0) * (dy ? wy1 : wy0);
            acc = fmaf(bil, wxy, acc);
        }
    }

    out[(size_t)n * RR + r] = acc;
}

extern "C" void kernel_launch(void* const* d_in, const int* in_sizes, int n_in,
                              void* d_out, int out_size, void* d_ws, size_t ws_size,
                              hipStream_t stream) {
    const float4* xyuv = (const float4*)d_in[0];
    const float*  grid = (const float*)d_in[1];
    const float*  mn   = (const float*)d_in[2];
    const float*  mx   = (const float*)d_in[3];
    float* out = (float*)d_out;

    int npts = in_sizes[0] / 4;
    int total = npts * RR;
    int block = 256;
    int nblocks = (total + block - 1) / block;
    grid4d_kernel<<<nblocks, block, 0, stream>>>(xyuv, grid, mn, mx, out, npts);
}

// Round 2
// 1696.516 us; speedup vs baseline: 1.1734x; 1.1734x over previous
//
#include <hip/hip_runtime.h>

// Grid4D quadrilinear sample, align_corners=True.
// grid: [R=8, X=9, Y=9, U=512, V=512] fp32 (648 MB), xyuv: [N,4] in [0,1]
// out: [N, 8] fp32
//
// Round 2: bucket-sort points by 16x16 (u,v) tile so that co-resident waves
// touch a small grid slab (~0.75 MB/tile) -> line revisits (avg ~6x) hit
// L2/L3 instead of HBM. Unique-line floor = 8*9*9*512*32 lines * 64 B = 0.68 GB
// (vs 4.3 GB fetched by the unsorted baseline, measured R1).

#define RR 8
#define SX 9
#define SY 9
#define SU 512
#define SV 512

#define NTU 32          // u tiles (512/16)
#define NTV 32          // v tiles
#define NTILES (NTU * NTV)

__device__ __forceinline__ void split_coord(float p, int size, int& i0, float& f) {
    p = fminf(fmaxf(p, 0.0f), (float)(size - 1));
    float fl = floorf(p);
    int i = (int)fl;
    if (i > size - 2) i = size - 2;   // keep i0+1 in bounds; f hits 1.0 at top edge
    i0 = i;
    f = p - (float)i;
}

__device__ __forceinline__ int tile_of(float4 c, const float* mn, const float* mx) {
    float pu = (c.z - mn[2]) / (mx[2] - mn[2]) * (float)(SU - 1);
    float pv = (c.w - mn[3]) / (mx[3] - mn[3]) * (float)(SV - 1);
    int u0, v0; float fu, fv;
    split_coord(pu, SU, u0, fu);
    split_coord(pv, SV, v0, fv);
    return (u0 >> 4) * NTV + (v0 >> 4);
}

__global__ void zero_kernel(int* p, int n) {
    int i = blockIdx.x * blockDim.x + threadIdx.x;
    if (i < n) p[i] = 0;
}

__global__ __launch_bounds__(256) void hist_kernel(
    const float4* __restrict__ xyuv, const float* __restrict__ mn,
    const float* __restrict__ mx, int* __restrict__ counts, int npts)
{
    __shared__ int h[NTILES];
    for (int i = threadIdx.x; i < NTILES; i += blockDim.x) h[i] = 0;
    __syncthreads();
    int stride = gridDim.x * blockDim.x;
    for (int n = blockIdx.x * blockDim.x + threadIdx.x; n < npts; n += stride)
        atomicAdd(&h[tile_of(xyuv[n], mn, mx)], 1);
    __syncthreads();
    for (int i = threadIdx.x; i < NTILES; i += blockDim.x)
        if (h[i]) atomicAdd(&counts[i], h[i]);
}

__global__ __launch_bounds__(NTILES) void scan_kernel(
    const int* __restrict__ counts, int* __restrict__ offsets)
{
    __shared__ int tmp[NTILES];
    int t = threadIdx.x;
    int my = counts[t];
    tmp[t] = my;
    __syncthreads();
    for (int d = 1; d < NTILES; d <<= 1) {
        int v = (t >= d) ? tmp[t - d] : 0;
        __syncthreads();
        tmp[t] += v;
        __syncthreads();
    }
    offsets[t] = tmp[t] - my;   // exclusive prefix
}

__global__ __launch_bounds__(256) void scatter_kernel(
    const float4* __restrict__ xyuv, const float* __restrict__ mn,
    const float* __restrict__ mx, int* __restrict__ cursor,
    float4* __restrict__ scoords, int* __restrict__ sidx, int npts)
{
    int stride = gridDim.x * blockDim.x;
    for (int n = blockIdx.x * blockDim.x + threadIdx.x; n < npts; n += stride) {
        float4 c = xyuv[n];
        int t = tile_of(c, mn, mx);
        int pos = atomicAdd(&cursor[t], 1);
        scoords[pos] = c;
        sidx[pos] = n;
    }
}

__global__ __launch_bounds__(256) void gather_kernel(
    const float4* __restrict__ scoords, const int* __restrict__ sidx,
    const float*  __restrict__ grid, const float* __restrict__ mn,
    const float*  __restrict__ mx, float* __restrict__ out, int npts)
{
    int tid = blockIdx.x * blockDim.x + threadIdx.x;
    int i = tid >> 3;
    int r = tid & 7;
    if (i >= npts) return;

    float4 c = scoords[i];
    int n = sidx[i];

    float px = (c.x - mn[0]) / (mx[0] - mn[0]) * (float)(SX - 1);
    float py = (c.y - mn[1]) / (mx[1] - mn[1]) * (float)(SY - 1);
    float pu = (c.z - mn[2]) / (mx[2] - mn[2]) * (float)(SU - 1);
    float pv = (c.w - mn[3]) / (mx[3] - mn[3]) * (float)(SV - 1);

    int x0, y0, u0, v0;
    float fx, fy, fu, fv;
    split_coord(px, SX, x0, fx);
    split_coord(py, SY, y0, fy);
    split_coord(pu, SU, u0, fu);
    split_coord(pv, SV, v0, fv);

    float wx0 = 1.0f - fx, wx1 = fx;
    float wy0 = 1.0f - fy, wy1 = fy;
    float wu0 = 1.0f - fu, wu1 = fu;
    float wv0 = 1.0f - fv, wv1 = fv;

    const float* gr = grid + (size_t)r * (SX * SY * SU * SV);
    size_t buv = (size_t)u0 * SV + (size_t)v0;

    float acc = 0.0f;
#pragma unroll
    for (int dx = 0; dx < 2; ++dx) {
#pragma unroll
        for (int dy = 0; dy < 2; ++dy) {
            const float* g = gr + ((size_t)(x0 + dx) * SY + (size_t)(y0 + dy)) * (SU * SV) + buv;
            float a00 = g[0];
            float a01 = g[1];
            float a10 = g[SV];
            float a11 = g[SV + 1];
            float bu0 = a00 * wv0 + a01 * wv1;
            float bu1 = a10 * wv0 + a11 * wv1;
            float bil = bu0 * wu0 + bu1 * wu1;
            float wxy = (dx ? wx1 : wx0) * (dy ? wy1 : wy0);
            acc = fmaf(bil, wxy, acc);
        }
    }

    out[(size_t)n * RR + r] = acc;
}

// Unsorted fallback (R1 baseline) if ws is too small.
__global__ __launch_bounds__(256) void grid4d_baseline(
    const float4* __restrict__ xyuv, const float* __restrict__ grid,
    const float* __restrict__ mn, const float* __restrict__ mx,
    float* __restrict__ out, int npts)
{
    int tid = blockIdx.x * blockDim.x + threadIdx.x;
    int n = tid >> 3;
    int r = tid & 7;
    if (n >= npts) return;
    float4 c = xyuv[n];
    float px = (c.x - mn[0]) / (mx[0] - mn[0]) * (float)(SX - 1);
    float py = (c.y - mn[1]) / (mx[1] - mn[1]) * (float)(SY - 1);
    float pu = (c.z - mn[2]) / (mx[2] - mn[2]) * (float)(SU - 1);
    float pv = (c.w - mn[3]) / (mx[3] - mn[3]) * (float)(SV - 1);
    int x0, y0, u0, v0; float fx, fy, fu, fv;
    split_coord(px, SX, x0, fx); split_coord(py, SY, y0, fy);
    split_coord(pu, SU, u0, fu); split_coord(pv, SV, v0, fv);
    float wx0 = 1.0f - fx, wx1 = fx, wy0 = 1.0f - fy, wy1 = fy;
    float wu0 = 1.0f - fu, wu1 = fu, wv0 = 1.0f - fv, wv1 = fv;
    const float* gr = grid + (size_t)r * (SX * SY * SU * SV);
    size_t buv = (size_t)u0 * SV + (size_t)v0;
    float acc = 0.0f;
#pragma unroll
    for (int dx = 0; dx < 2; ++dx)
#pragma unroll
        for (int dy = 0; dy < 2; ++dy) {
            const float* g = gr + ((size_t)(x0 + dx) * SY + (size_t)(y0 + dy)) * (SU * SV) + buv;
            float bu0 = g[0] * wv0 + g[1] * wv1;
            float bu1 = g[SV] * wv0 + g[SV + 1] * wv1;
            float wxy = (dx ? wx1 : wx0) * (dy ? wy1 : wy0);
            acc = fmaf(bu0 * wu0 + bu1 * wu1, wxy, acc);
        }
    out[(size_t)n * RR + r] = acc;
}

extern "C" void kernel_launch(void* const* d_in, const int* in_sizes, int n_in,
                              void* d_out, int out_size, void* d_ws, size_t ws_size,
                              hipStream_t stream) {
    const float4* xyuv = (const float4*)d_in[0];
    const float*  grid = (const float*)d_in[1];
    const float*  mn   = (const float*)d_in[2];
    const float*  mx   = (const float*)d_in[3];
    float* out = (float*)d_out;

    int npts = in_sizes[0] / 4;

    // ws carve: counts[NTILES] | offsets[NTILES] | scoords[npts] (16B-aligned) | sidx[npts]
    size_t off_counts  = 0;
    size_t off_offsets = off_counts + NTILES * sizeof(int);
    size_t off_scoords = (off_offsets + NTILES * sizeof(int) + 15) & ~(size_t)15;
    size_t off_sidx    = off_scoords + (size_t)npts * sizeof(float4);
    size_t needed      = off_sidx + (size_t)npts * sizeof(int);

    if (ws_size < needed) {
        int total = npts * RR;
        grid4d_baseline<<<(total + 255) / 256, 256, 0, stream>>>(xyuv, grid, mn, mx, out, npts);
        return;
    }

    char* ws = (char*)d_ws;
    int*    counts  = (int*)(ws + off_counts);
    int*    offsets = (int*)(ws + off_offsets);
    float4* scoords = (float4*)(ws + off_scoords);
    int*    sidx    = (int*)(ws + off_sidx);

    zero_kernel<<<(NTILES + 255) / 256, 256, 0, stream>>>(counts, NTILES);
    hist_kernel<<<256, 256, 0, stream>>>(xyuv, mn, mx, counts, npts);
    scan_kernel<<<1, NTILES, 0, stream>>>(counts, offsets);
    scatter_kernel<<<1024, 256, 0, stream>>>(xyuv, mn, mx, offsets, scoords, sidx, npts);

    int total = npts * RR;
    gather_kernel<<<(total + 255) / 256, 256, 0, stream>>>(scoords, sidx, grid, mn, mx, out, npts);
}